// Round 12
// baseline (234.105 us; speedup 1.0000x reference)
//
#include <hip/hip_runtime.h>
#include <hip/hip_bf16.h>

// Problem constants (B=2, P=2048, D=768, H=12, hd=64)
#define B_  2
#define P_  2048
#define D_  768
#define H_  12
#define HD_ 64
#define M_  (B_ * P_)   // 4096
#define N1_ (3 * D_)    // 2304

typedef __attribute__((ext_vector_type(8))) short short8;    // 8 bf16 (4 VGPRs)
typedef __attribute__((ext_vector_type(4))) float f32x4;     // 16x16 MFMA acc
typedef __attribute__((ext_vector_type(16))) float f32x16;   // 32x32 MFMA acc
typedef __attribute__((ext_vector_type(4))) unsigned u32x4;
typedef unsigned short ushort;

__device__ __forceinline__ ushort f2bf(float f) {
    unsigned u = __float_as_uint(f);
    u += 0x7fffu + ((u >> 16) & 1u);   // RNE
    return (ushort)(u >> 16);
}

// Pack 2 floats -> 1 dword of 2x bf16 (lo=a, hi=b), RNE. HW-verified (r5/r6).
__device__ __forceinline__ unsigned cvtpk(float a, float b) {
    unsigned r;
    asm("v_cvt_pk_bf16_f32 %0, %1, %2" : "=v"(r) : "v"(a), "v"(b));
    return r;
}

__device__ __forceinline__ float bf2f(ushort u) {
    return __uint_as_float((unsigned)u << 16);
}

// Swap bits 2 and 3 of a slot index (involution) — attn K staging permutation.
__device__ __forceinline__ int swap23(int s) {
    return (s & ~12) | ((s & 4) << 1) | ((s & 8) >> 1);
}

// Q pre-scale: hd^-0.5 * log2(e) — attn uses exp2 directly.
#define QSC_ (0.125f * 1.44269504088896340736f)

// ===========================================================================
// Kernel 0: one-shot fp32 -> bf16 precast of x, W_qkv, W_out. (unchanged)
// ===========================================================================
__global__ __launch_bounds__(256) void precast(const float* __restrict__ x,
                                               const float* __restrict__ wqkv,
                                               const float* __restrict__ wout,
                                               ushort* __restrict__ xb,
                                               ushort* __restrict__ wqb,
                                               ushort* __restrict__ wob) {
    const int stride = gridDim.x * 256;
    int tid = blockIdx.x * 256 + threadIdx.x;
    const int nx = M_ * D_ / 4, nq = D_ * N1_ / 4, no = D_ * D_ / 4;
    for (int i = tid; i < nx; i += stride) {
        float4 v = ((const float4*)x)[i];
        ((uint2*)xb)[i] = {cvtpk(v.x, v.y), cvtpk(v.z, v.w)};
    }
    for (int i = tid; i < nq; i += stride) {
        float4 v = ((const float4*)wqkv)[i];
        ((uint2*)wqb)[i] = {cvtpk(v.x, v.y), cvtpk(v.z, v.w)};
    }
    for (int i = tid; i < no; i += stride) {
        float4 v = ((const float4*)wout)[i];
        ((uint2*)wob)[i] = {cvtpk(v.x, v.y), cvtpk(v.z, v.w)};
    }
}

// ===========================================================================
// Kernel 1 (R12): qkv = x_bf16 @ Wqkv_bf16 + fused per-head QK-LayerNorm.
// 128x128 tile, BK=64 (12 K-steps, 24 barriers vs 48), 512 thr / 8 waves,
// single-buffered LDS 36.9KB (still 4 blocks/CU at 512 thr). Padded [.][72]:
// lane stride 144B = 4 banks -> 2-way aliasing (free, m136).
// ===========================================================================
__global__ __launch_bounds__(512) void gemm_qkv_mfma(
        const ushort* __restrict__ x, const ushort* __restrict__ w,
        const float* __restrict__ qs, const float* __restrict__ qb,
        const float* __restrict__ ks, const float* __restrict__ kb,
        ushort* __restrict__ qkv) {
    __shared__ __align__(16) ushort As[128][72];
    __shared__ __align__(16) ushort Bs[128][72];

    const int tid  = threadIdx.x;
    const int lane = tid & 63;
    const int wv   = tid >> 6;            // 0..7
    const int quad = lane >> 4;
    const int col  = lane & 15;
    const int wr   = (wv >> 1) * 32;
    const int wc   = (wv & 1) * 64;
    const int rowBase = blockIdx.y * 128;
    const int colBase = blockIdx.x * 128;

    const int amr = tid >> 2, ac4 = tid & 3;    // A: row 0..127, chunk 0..3 (+4)
    const int nB  = tid & 127, kq = tid >> 7;   // B: n 0..127, k-group 0..3 (16 rows)

    uint4  apre[2];
    ushort bpre[16];
    auto load_tile = [&](int kt) {
        const int k0 = kt * 64;
        apre[0] = *(const uint4*)(x + (size_t)(rowBase + amr) * D_ + k0 + ac4 * 8);
        apre[1] = *(const uint4*)(x + (size_t)(rowBase + amr) * D_ + k0 + (ac4 + 4) * 8);
#pragma unroll
        for (int j = 0; j < 16; j++)
            bpre[j] = w[(size_t)(k0 + kq * 16 + j) * N1_ + colBase + nB];
    };

    f32x4 acc[2][4];
#pragma unroll
    for (int i = 0; i < 2; i++)
#pragma unroll
        for (int j = 0; j < 4; j++) acc[i][j] = (f32x4){0.f, 0.f, 0.f, 0.f};

    load_tile(0);
    const int NT = D_ / 64;               // 12
    for (int kt = 0; kt < NT; kt++) {
        __syncthreads();
        *(uint4*)&As[amr][ac4 * 8]       = apre[0];
        *(uint4*)&As[amr][(ac4 + 4) * 8] = apre[1];
        *(short8*)&Bs[nB][kq * 16]       = *(short8*)&bpre[0];
        *(short8*)&Bs[nB][kq * 16 + 8]   = *(short8*)&bpre[8];
        __syncthreads();
        if (kt + 1 < NT) load_tile(kt + 1);

#pragma unroll
        for (int k32 = 0; k32 < 2; k32++) {
            short8 af[2], bf[4];
#pragma unroll
            for (int mt = 0; mt < 2; mt++)
                af[mt] = *(const short8*)&As[wr + mt * 16 + col][k32 * 32 + quad * 8];
#pragma unroll
            for (int nt = 0; nt < 4; nt++)
                bf[nt] = *(const short8*)&Bs[wc + nt * 16 + col][k32 * 32 + quad * 8];
#pragma unroll
            for (int mt = 0; mt < 2; mt++)
#pragma unroll
                for (int nt = 0; nt < 4; nt++)
                    acc[mt][nt] = __builtin_amdgcn_mfma_f32_16x16x32_bf16(af[mt], bf[nt], acc[mt][nt], 0, 0, 0);
        }
    }

    const int comp = colBase / D_;
    const int rem  = colBase + wc - comp * D_;
    const int h    = rem >> 6;
    float sc4[4] = {0, 0, 0, 0}, bi4[4] = {0, 0, 0, 0};
    if (comp == 0) {
#pragma unroll
        for (int nt = 0; nt < 4; nt++) { sc4[nt] = qs[nt * 16 + col]; bi4[nt] = qb[nt * 16 + col]; }
    } else if (comp == 1) {
#pragma unroll
        for (int nt = 0; nt < 4; nt++) { sc4[nt] = ks[nt * 16 + col]; bi4[nt] = kb[nt * 16 + col]; }
    }

#pragma unroll
    for (int mt = 0; mt < 2; mt++) {
#pragma unroll
        for (int r = 0; r < 4; r++) {
            int m  = rowBase + wr + mt * 16 + quad * 4 + r;
            int bb = m >> 11;
            int p  = m & 2047;
            float v0 = acc[mt][0][r], v1 = acc[mt][1][r], v2 = acc[mt][2][r], v3 = acc[mt][3][r];
            if (comp < 2) {
                float s = v0 + v1 + v2 + v3;
#pragma unroll
                for (int off = 1; off < 16; off <<= 1) s += __shfl_xor(s, off, 64);
                float mean = s * (1.0f / 64.0f);
                float d0 = v0 - mean, d1 = v1 - mean, d2 = v2 - mean, d3 = v3 - mean;
                float sq = d0 * d0 + d1 * d1 + d2 * d2 + d3 * d3;
#pragma unroll
                for (int off = 1; off < 16; off <<= 1) sq += __shfl_xor(sq, off, 64);
                float inv = rsqrtf(sq * (1.0f / 64.0f) + 1e-6f);
                v0 = d0 * inv * sc4[0] + bi4[0];
                v1 = d1 * inv * sc4[1] + bi4[1];
                v2 = d2 * inv * sc4[2] + bi4[2];
                v3 = d3 * inv * sc4[3] + bi4[3];
                if (comp == 0) { v0 *= QSC_; v1 *= QSC_; v2 *= QSC_; v3 *= QSC_; }
            }
            size_t base = ((((size_t)comp * B_ + bb) * H_ + h) * P_ + p) * HD_;
            qkv[base +  0 + col] = f2bf(v0);
            qkv[base + 16 + col] = f2bf(v1);
            qkv[base + 32 + col] = f2bf(v2);
            qkv[base + 48 + col] = f2bf(v3);
        }
    }
}

// ===========================================================================
// Kernel 2: flash attention (unchanged R11 — 64 q/wave, swapped QK^T,
// swap23, double-buffered K/V, exp2, in-register P, setprio, bf16 partials).
// ===========================================================================
__global__ __launch_bounds__(256) void attn_split(const ushort* __restrict__ qkv,
                                                  ushort* __restrict__ o0, ushort* __restrict__ o1,
                                                  ushort* __restrict__ o2, ushort* __restrict__ o3,
                                                  float* __restrict__ l0, float* __restrict__ l1,
                                                  float* __restrict__ l2, float* __restrict__ l3) {
    const int p0  = blockIdx.x * 256;
    const int bh  = blockIdx.y;
    const int s   = blockIdx.z;
    const int nsp = gridDim.z;           // 2 or 4
    const int b   = bh / H_, h = bh % H_;
    ushort* opart = (s == 0) ? o0 : (s == 1) ? o1 : (s == 2) ? o2 : o3;
    float*  lpart = (s == 0) ? l0 : (s == 1) ? l1 : (s == 2) ? l2 : l3;
    const int tid  = threadIdx.x;
    const int lane = tid & 63;
    const int wv   = tid >> 6;
    const int half = lane >> 5;     // 0/1
    const int n32  = lane & 31;     // q-column of this lane

    __shared__ __align__(16) ushort KVs[2][2][64][72];

    const size_t hs  = (size_t)P_ * HD_;
    const int    kv0 = s * (P_ / nsp);
    const ushort* qg = qkv + ((size_t)(0 * B_ + b) * H_ + h) * hs + (size_t)(p0 + wv * 64) * HD_;
    const ushort* kg = qkv + ((size_t)(1 * B_ + b) * H_ + h) * hs + (size_t)kv0 * HD_;
    const ushort* vg = qkv + ((size_t)(2 * B_ + b) * H_ + h) * hs + (size_t)kv0 * HD_;

    short8 aq[2][4];
#pragma unroll
    for (int qs2 = 0; qs2 < 2; qs2++)
#pragma unroll
        for (int ks2 = 0; ks2 < 4; ks2++)
            aq[qs2][ks2] = *(const short8*)(qg + (size_t)(qs2 * 32 + n32) * HD_ + ks2 * 16 + half * 8);

    float lsum[2] = {0.f, 0.f};
    f32x16 oaccT[2][2];                  // [qsub][ntd]
#pragma unroll
    for (int q2 = 0; q2 < 2; q2++)
#pragma unroll
        for (int nt = 0; nt < 2; nt++)
#pragma unroll
            for (int r = 0; r < 16; r++) oaccT[q2][nt][r] = 0.f;

    const int kr = tid >> 3, kc8 = tid & 7;
    const int krs = swap23(kr);
    const int vd = tid & 63,  vkh = tid >> 6;

    uint4  kpre[2];
    ushort vpre[16];
    auto load_tile = [&](int kt) {
        const ushort* kg_t = kg + (size_t)kt * 64 * HD_;
        const ushort* vg_t = vg + (size_t)kt * 64 * HD_;
        kpre[0] = *(const uint4*)(kg_t + (size_t)kr * HD_ + kc8 * 8);
        kpre[1] = *(const uint4*)(kg_t + (size_t)(kr + 32) * HD_ + kc8 * 8);
#pragma unroll
        for (int j = 0; j < 16; j++)
            vpre[j] = vg_t[(size_t)(vkh * 16 + j) * HD_ + vd];
    };
    auto stage = [&](int buf) {
        *(uint4*)&KVs[buf][0][krs][kc8 * 8]      = kpre[0];
        *(uint4*)&KVs[buf][0][krs + 32][kc8 * 8] = kpre[1];
        *(short8*)&KVs[buf][1][vd][vkh * 16]     = *(short8*)&vpre[0];
        *(short8*)&KVs[buf][1][vd][vkh * 16 + 8] = *(short8*)&vpre[8];
    };

    load_tile(0);
    stage(0);
    __syncthreads();

    const int NT = (P_ / 64) / nsp;      // 8 (nsp=4) or 16 (nsp=2) — even
    int cur = 0;
    for (int kt = 0; kt < NT; kt++) {
        const bool more = (kt + 1 < NT);
        if (more) load_tile(kt + 1);

        ushort (*Ks)[72] = KVs[cur][0];
        ushort (*Vs)[72] = KVs[cur][1];

#pragma unroll
        for (int nt = 0; nt < 2; nt++) {
#pragma unroll
            for (int q2 = 0; q2 < 2; q2++) {
                f32x16 sc;
#pragma unroll
                for (int r = 0; r < 16; r++) sc[r] = 0.f;
                __builtin_amdgcn_s_setprio(1);
#pragma unroll
                for (int ks2 = 0; ks2 < 4; ks2++) {
                    short8 kb2 = *(const short8*)&Ks[nt * 32 + n32][ks2 * 16 + half * 8];
                    sc = __builtin_amdgcn_mfma_f32_32x32x16_bf16(kb2, aq[q2][ks2], sc, 0, 0, 0);
                }
                __builtin_amdgcn_s_setprio(0);
                float p[16];
#pragma unroll
                for (int r = 0; r < 16; r++) {
                    p[r] = __builtin_amdgcn_exp2f(sc[r]);
                    lsum[q2] += p[r];
                }
                unsigned w[8];
#pragma unroll
                for (int i = 0; i < 8; i++) w[i] = cvtpk(p[2 * i], p[2 * i + 1]);
                __builtin_amdgcn_s_setprio(1);
#pragma unroll
                for (int kp2 = 0; kp2 < 2; kp2++) {
                    u32x4 t = {w[kp2 * 4 + 0], w[kp2 * 4 + 1], w[kp2 * 4 + 2], w[kp2 * 4 + 3]};
                    short8 pb = __builtin_bit_cast(short8, t);
                    const int kstep = nt * 2 + kp2;
#pragma unroll
                    for (int ntd = 0; ntd < 2; ntd++) {
                        short8 av = *(const short8*)&Vs[ntd * 32 + n32][kstep * 16 + half * 8];
                        oaccT[q2][ntd] = __builtin_amdgcn_mfma_f32_32x32x16_bf16(av, pb, oaccT[q2][ntd], 0, 0, 0);
                    }
                }
                __builtin_amdgcn_s_setprio(0);
            }
        }

        if (more) {
            stage(cur ^ 1);
            __syncthreads();
            cur ^= 1;
        }
    }

#pragma unroll
    for (int q2 = 0; q2 < 2; q2++)
        lsum[q2] += __shfl_xor(lsum[q2], 32, 64);
    if (lane < 32) {
        lpart[(size_t)bh * P_ + p0 + wv * 64 +  0 + lane] = lsum[0];
        lpart[(size_t)bh * P_ + p0 + wv * 64 + 32 + lane] = lsum[1];
    }

    float* scr = (float*)&KVs[0][0][0][0] + wv * 1152;
#pragma unroll
    for (int q2 = 0; q2 < 2; q2++) {
#pragma unroll
        for (int ntd = 0; ntd < 2; ntd++) {
#pragma unroll
            for (int r = 0; r < 16; r++)
                scr[n32 * 36 + (r & 3) + 8 * (r >> 2) + 4 * half] = oaccT[q2][ntd][r];
#pragma unroll
            for (int i = 0; i < 4; i++) {
                int ql = i * 8 + (lane >> 3);
                int c4 = lane & 7;
                float4 v = *(const float4*)&scr[ql * 36 + c4 * 4];
                uint2 pk = {cvtpk(v.x, v.y), cvtpk(v.z, v.w)};
                *(uint2*)(opart + ((size_t)bh * P_ + p0 + wv * 64 + q2 * 32 + ql) * HD_ + ntd * 32 + c4 * 4) = pk;
            }
        }
    }
}

// ===========================================================================
// Kernel 3: LayerNorm over D=768, fused split-combine of bf16 partials.
// (unchanged)
// ===========================================================================
__global__ __launch_bounds__(256) void ln_o(const ushort* __restrict__ o0,
                                            const ushort* __restrict__ o1,
                                            const ushort* __restrict__ o2,
                                            const ushort* __restrict__ o3,
                                            const float* __restrict__ l0,
                                            const float* __restrict__ l1,
                                            const float* __restrict__ l2,
                                            const float* __restrict__ l3,
                                            const int ns,
                                            ushort* __restrict__ lnb,
                                            const float* __restrict__ osc,
                                            const float* __restrict__ ob) {
    __shared__ float red[4];
    __shared__ float red2[4];
    const int row = blockIdx.x;          // b*P + p
    const int b   = row >> 11;
    const int p   = row & (P_ - 1);
    const int tid = threadIdx.x;

    auto src = [&](int d) {
        int h = d >> 6;
        size_t lr  = (size_t)(b * H_ + h) * P_ + p;
        size_t idx = lr * HD_ + (d & 63);
        float num = bf2f(o0[idx]) + bf2f(o1[idx]);
        float den = l0[lr] + l1[lr];
        if (ns == 4) { num += bf2f(o2[idx]) + bf2f(o3[idx]); den += l2[lr] + l3[lr]; }
        return num / den;
    };
    float v0 = src(tid);
    float v1 = src(tid + 256);
    float v2 = src(tid + 512);
    float s = v0 + v1 + v2;
#pragma unroll
    for (int o = 32; o > 0; o >>= 1) s += __shfl_xor(s, o, 64);
    if ((tid & 63) == 0) red[tid >> 6] = s;
    __syncthreads();
    float mean = (red[0] + red[1] + red[2] + red[3]) * (1.0f / 768.0f);
    float d0 = v0 - mean, d1 = v1 - mean, d2 = v2 - mean;
    float sq = d0 * d0 + d1 * d1 + d2 * d2;
#pragma unroll
    for (int o = 32; o > 0; o >>= 1) sq += __shfl_xor(sq, o, 64);
    if ((tid & 63) == 0) red2[tid >> 6] = sq;
    __syncthreads();
    float var = (red2[0] + red2[1] + red2[2] + red2[3]) * (1.0f / 768.0f);
    float inv = rsqrtf(var + 1e-6f);
    const size_t base = (size_t)row * D_;
    lnb[base + tid]       = f2bf(d0 * inv * osc[tid]       + ob[tid]);
    lnb[base + tid + 256] = f2bf(d1 * inv * osc[tid + 256] + ob[tid + 256]);
    lnb[base + tid + 512] = f2bf(d2 * inv * osc[tid + 512] + ob[tid + 512]);
}

// ===========================================================================
// Kernel 4 (R12): out = ln_buf(bf16) @ Wout_bf16 + b_out. 64x64 tile,
// BK=64 (12 steps), 256 thr, single-buffered padded LDS (18.4KB).
// ===========================================================================
__global__ __launch_bounds__(256) void gemm_out_mfma(
        const ushort* __restrict__ a, const ushort* __restrict__ w,
        const float* __restrict__ bias, float* __restrict__ out) {
    __shared__ __align__(16) ushort As[64][72];
    __shared__ __align__(16) ushort Bs[64][72];

    const int tid  = threadIdx.x;
    const int lane = tid & 63;
    const int wv   = tid >> 6;
    const int quad = lane >> 4;
    const int col  = lane & 15;
    const int wr   = (wv >> 1) * 32;
    const int wc   = (wv & 1) * 32;
    const int rowBase = blockIdx.y * 64;
    const int colBase = blockIdx.x * 64;

    const int am  = tid >> 2, ac4 = tid & 3;    // A: row 0..63, chunk 0..3 (+4)
    const int nB  = tid & 63, kq = tid >> 6;    // B: n 0..63, k-group 0..3

    uint4  apre[2];
    ushort bpre[16];
    auto load_tile = [&](int kt) {
        const int k0 = kt * 64;
        apre[0] = *(const uint4*)(a + (size_t)(rowBase + am) * D_ + k0 + ac4 * 8);
        apre[1] = *(const uint4*)(a + (size_t)(rowBase + am) * D_ + k0 + (ac4 + 4) * 8);
#pragma unroll
        for (int j = 0; j < 16; j++)
            bpre[j] = w[(size_t)(k0 + kq * 16 + j) * D_ + colBase + nB];
    };

    f32x4 acc[2][2];
#pragma unroll
    for (int i = 0; i < 2; i++)
#pragma unroll
        for (int j = 0; j < 2; j++) acc[i][j] = (f32x4){0.f, 0.f, 0.f, 0.f};

    load_tile(0);
    const int NT = D_ / 64;               // 12
    for (int kt = 0; kt < NT; kt++) {
        __syncthreads();
        *(uint4*)&As[am][ac4 * 8]       = apre[0];
        *(uint4*)&As[am][(ac4 + 4) * 8] = apre[1];
        *(short8*)&Bs[nB][kq * 16]      = *(short8*)&bpre[0];
        *(short8*)&Bs[nB][kq * 16 + 8]  = *(short8*)&bpre[8];
        __syncthreads();
        if (kt + 1 < NT) load_tile(kt + 1);

#pragma unroll
        for (int k32 = 0; k32 < 2; k32++) {
            short8 af[2], bf[2];
#pragma unroll
            for (int mt = 0; mt < 2; mt++)
                af[mt] = *(const short8*)&As[wr + mt * 16 + col][k32 * 32 + quad * 8];
#pragma unroll
            for (int nt = 0; nt < 2; nt++)
                bf[nt] = *(const short8*)&Bs[wc + nt * 16 + col][k32 * 32 + quad * 8];
#pragma unroll
            for (int mt = 0; mt < 2; mt++)
#pragma unroll
                for (int nt = 0; nt < 2; nt++)
                    acc[mt][nt] = __builtin_amdgcn_mfma_f32_16x16x32_bf16(af[mt], bf[nt], acc[mt][nt], 0, 0, 0);
        }
    }

    float b2[2];
#pragma unroll
    for (int nt = 0; nt < 2; nt++) b2[nt] = bias[colBase + wc + nt * 16 + col];
#pragma unroll
    for (int mt = 0; mt < 2; mt++) {
#pragma unroll
        for (int r = 0; r < 4; r++) {
            int m = rowBase + wr + mt * 16 + quad * 4 + r;
            float* dst = out + (size_t)m * D_ + colBase + wc;
#pragma unroll
            for (int nt = 0; nt < 2; nt++)
                dst[nt * 16 + col] = acc[mt][nt][r] + b2[nt];
        }
    }
}

// ---------------------------------------------------------------------------
extern "C" void kernel_launch(void* const* d_in, const int* in_sizes, int n_in,
                              void* d_out, int out_size, void* d_ws, size_t ws_size,
                              hipStream_t stream) {
    const float* x    = (const float*)d_in[0];
    const float* Wqkv = (const float*)d_in[1];
    const float* qs   = (const float*)d_in[2];
    const float* qb   = (const float*)d_in[3];
    const float* ks   = (const float*)d_in[4];
    const float* kb   = (const float*)d_in[5];
    const float* osc  = (const float*)d_in[6];
    const float* ob   = (const float*)d_in[7];
    const float* Wout = (const float*)d_in[8];
    const float* bout = (const float*)d_in[9];
    float* out = (float*)d_out;

    // Workspace: qkv bf16 18.9MB | (nsp-1) bf16 O-partials | nsp fp32 l |
    // bf16 casts of x (6.3MB), Wqkv (3.5MB), Wout (1.2MB).
    ushort* qkv = (ushort*)d_ws;
    const size_t qkvE  = (size_t)3 * B_ * H_ * P_ * HD_;
    const size_t oE    = (size_t)B_ * H_ * P_ * HD_;
    const size_t lE    = (size_t)B_ * H_ * P_;
    const size_t castE = (size_t)M_ * D_ + (size_t)D_ * N1_ + (size_t)D_ * D_;
    ushort* obase = qkv + qkvE;
    const size_t need4 = (qkvE + 3 * oE + castE) * sizeof(ushort) + 4 * lE * sizeof(float);
    const int nsp = (ws_size >= need4) ? 4 : 2;
    ushort* op[4];
    float* lbase;
    if (nsp == 4) {
        op[0] = obase; op[1] = obase + oE; op[2] = obase + 2 * oE; op[3] = (ushort*)out;
        lbase = (float*)(obase + 3 * oE);
    } else {
        op[0] = obase; op[1] = (ushort*)out; op[2] = obase; op[3] = obase;
        lbase = (float*)(obase + oE);
    }
    float* lp[4] = {lbase, lbase + lE, lbase + 2 * lE, lbase + 3 * lE};
    ushort* xb  = (ushort*)(lp[0] + 4 * lE);
    ushort* wqb = xb + (size_t)M_ * D_;
    ushort* wob = wqb + (size_t)D_ * N1_;
    ushort* ln_buf = qkv;   // overlays dead q-region after attention

    precast<<<dim3(1024), 256, 0, stream>>>(x, Wqkv, Wout, xb, wqb, wob);
    gemm_qkv_mfma<<<dim3(N1_ / 128, M_ / 128), 512, 0, stream>>>(xb, wqb, qs, qb, ks, kb, qkv);
    attn_split<<<dim3(P_ / 256, B_ * H_, nsp), 256, 0, stream>>>(
        qkv, op[0], op[1], op[2], op[3], lp[0], lp[1], lp[2], lp[3]);
    ln_o<<<dim3(M_), 256, 0, stream>>>(
        op[0], op[1], op[2], op[3], lp[0], lp[1], lp[2], lp[3], nsp, ln_buf, osc, ob);
    gemm_out_mfma<<<dim3(D_ / 64, M_ / 64), 256, 0, stream>>>(ln_buf, wob, bout, out);
}

// Round 13
// 197.448 us; speedup vs baseline: 1.1857x; 1.1857x over previous
//
#include <hip/hip_runtime.h>
#include <hip/hip_bf16.h>

// Problem constants (B=2, P=2048, D=768, H=12, hd=64)
#define B_  2
#define P_  2048
#define D_  768
#define H_  12
#define HD_ 64
#define M_  (B_ * P_)   // 4096
#define N1_ (3 * D_)    // 2304

typedef __attribute__((ext_vector_type(8))) short short8;    // 8 bf16 (4 VGPRs)
typedef __attribute__((ext_vector_type(4))) float f32x4;     // 16x16 MFMA acc
typedef __attribute__((ext_vector_type(16))) float f32x16;   // 32x32 MFMA acc
typedef __attribute__((ext_vector_type(4))) unsigned u32x4;
typedef unsigned short ushort;

__device__ __forceinline__ ushort f2bf(float f) {
    unsigned u = __float_as_uint(f);
    u += 0x7fffu + ((u >> 16) & 1u);   // RNE
    return (ushort)(u >> 16);
}

// Pack 2 floats -> 1 dword of 2x bf16 (lo=a, hi=b), RNE. HW-verified (r5/r6).
__device__ __forceinline__ unsigned cvtpk(float a, float b) {
    unsigned r;
    asm("v_cvt_pk_bf16_f32 %0, %1, %2" : "=v"(r) : "v"(a), "v"(b));
    return r;
}

__device__ __forceinline__ float bf2f(ushort u) {
    return __uint_as_float((unsigned)u << 16);
}

// Swap bits 2 and 3 of a slot index (involution) — attn K staging permutation.
__device__ __forceinline__ int swap23(int s) {
    return (s & ~12) | ((s & 4) << 1) | ((s & 8) >> 1);
}

// Q pre-scale: hd^-0.5 * log2(e) — attn uses exp2 directly.
#define QSC_ (0.125f * 1.44269504088896340736f)

// ===========================================================================
// Kernel 1 (R7-verified config): qkv = x @ W_qkv + fused per-head QK-LN.
// 128x128 tile, BK=32, 512 thr / 8 waves, single-buffered padded LDS,
// cvtpk staging. This structure measured best across R8/R9/R12 alternatives.
// ===========================================================================
__global__ __launch_bounds__(512) void gemm_qkv_mfma(
        const float* __restrict__ x, const float* __restrict__ w,
        const float* __restrict__ qs, const float* __restrict__ qb,
        const float* __restrict__ ks, const float* __restrict__ kb,
        ushort* __restrict__ qkv) {
    __shared__ __align__(16) ushort As[128][40];
    __shared__ __align__(16) ushort Bs[128][40];

    const int tid  = threadIdx.x;
    const int lane = tid & 63;
    const int wv   = tid >> 6;            // 0..7
    const int quad = lane >> 4;
    const int col  = lane & 15;
    const int wr   = (wv >> 1) * 32;
    const int wc   = (wv & 1) * 64;
    const int rowBase = blockIdx.y * 128;
    const int colBase = blockIdx.x * 128;

    const int am0 = tid >> 3, ac4 = tid & 7;
    const int nB  = tid & 127, kq = tid >> 7;

    float4 apre[2];
    float  bpre[8];
    auto load_tile = [&](int kt) {
        const int k0 = kt * 32;
        apre[0] = *(const float4*)(x + (size_t)(rowBase + am0) * D_ + k0 + ac4 * 4);
        apre[1] = *(const float4*)(x + (size_t)(rowBase + am0 + 64) * D_ + k0 + ac4 * 4);
#pragma unroll
        for (int j = 0; j < 8; j++)
            bpre[j] = w[(size_t)(k0 + kq * 8 + j) * N1_ + colBase + nB];
    };

    f32x4 acc[2][4];
#pragma unroll
    for (int i = 0; i < 2; i++)
#pragma unroll
        for (int j = 0; j < 4; j++) acc[i][j] = (f32x4){0.f, 0.f, 0.f, 0.f};

    load_tile(0);
    const int NT = D_ / 32;
    for (int kt = 0; kt < NT; kt++) {
        __syncthreads();
        {
            uint2 a0 = {cvtpk(apre[0].x, apre[0].y), cvtpk(apre[0].z, apre[0].w)};
            uint2 a1 = {cvtpk(apre[1].x, apre[1].y), cvtpk(apre[1].z, apre[1].w)};
            *(uint2*)&As[am0][ac4 * 4]      = a0;
            *(uint2*)&As[am0 + 64][ac4 * 4] = a1;
            u32x4 bb;
#pragma unroll
            for (int j = 0; j < 4; j++) bb[j] = cvtpk(bpre[2 * j], bpre[2 * j + 1]);
            *(u32x4*)&Bs[nB][kq * 8] = bb;
        }
        __syncthreads();
        if (kt + 1 < NT) load_tile(kt + 1);

        short8 af[2], bf[4];
#pragma unroll
        for (int mt = 0; mt < 2; mt++) af[mt] = *(const short8*)&As[wr + mt * 16 + col][quad * 8];
#pragma unroll
        for (int nt = 0; nt < 4; nt++) bf[nt] = *(const short8*)&Bs[wc + nt * 16 + col][quad * 8];
#pragma unroll
        for (int mt = 0; mt < 2; mt++)
#pragma unroll
            for (int nt = 0; nt < 4; nt++)
                acc[mt][nt] = __builtin_amdgcn_mfma_f32_16x16x32_bf16(af[mt], bf[nt], acc[mt][nt], 0, 0, 0);
    }

    const int comp = colBase / D_;
    const int rem  = colBase + wc - comp * D_;
    const int h    = rem >> 6;
    float sc4[4] = {0, 0, 0, 0}, bi4[4] = {0, 0, 0, 0};
    if (comp == 0) {
#pragma unroll
        for (int nt = 0; nt < 4; nt++) { sc4[nt] = qs[nt * 16 + col]; bi4[nt] = qb[nt * 16 + col]; }
    } else if (comp == 1) {
#pragma unroll
        for (int nt = 0; nt < 4; nt++) { sc4[nt] = ks[nt * 16 + col]; bi4[nt] = kb[nt * 16 + col]; }
    }

#pragma unroll
    for (int mt = 0; mt < 2; mt++) {
#pragma unroll
        for (int r = 0; r < 4; r++) {
            int m  = rowBase + wr + mt * 16 + quad * 4 + r;
            int bb = m >> 11;
            int p  = m & 2047;
            float v0 = acc[mt][0][r], v1 = acc[mt][1][r], v2 = acc[mt][2][r], v3 = acc[mt][3][r];
            if (comp < 2) {
                float s = v0 + v1 + v2 + v3;
#pragma unroll
                for (int off = 1; off < 16; off <<= 1) s += __shfl_xor(s, off, 64);
                float mean = s * (1.0f / 64.0f);
                float d0 = v0 - mean, d1 = v1 - mean, d2 = v2 - mean, d3 = v3 - mean;
                float sq = d0 * d0 + d1 * d1 + d2 * d2 + d3 * d3;
#pragma unroll
                for (int off = 1; off < 16; off <<= 1) sq += __shfl_xor(sq, off, 64);
                float inv = rsqrtf(sq * (1.0f / 64.0f) + 1e-6f);
                v0 = d0 * inv * sc4[0] + bi4[0];
                v1 = d1 * inv * sc4[1] + bi4[1];
                v2 = d2 * inv * sc4[2] + bi4[2];
                v3 = d3 * inv * sc4[3] + bi4[3];
                if (comp == 0) { v0 *= QSC_; v1 *= QSC_; v2 *= QSC_; v3 *= QSC_; }
            }
            size_t base = ((((size_t)comp * B_ + bb) * H_ + h) * P_ + p) * HD_;
            qkv[base +  0 + col] = f2bf(v0);
            qkv[base + 16 + col] = f2bf(v1);
            qkv[base + 32 + col] = f2bf(v2);
            qkv[base + 48 + col] = f2bf(v3);
        }
    }
}

// ===========================================================================
// Kernel 2 (R11-verified): flash attention, 64 q per wave, block = 256 q.
// Swapped QK^T + swap23 staging + exp2 softmax + in-register P + setprio +
// bf16 partial-O. Double-buffered K/V LDS, one barrier per 64-key tile.
// ===========================================================================
__global__ __launch_bounds__(256) void attn_split(const ushort* __restrict__ qkv,
                                                  ushort* __restrict__ o0, ushort* __restrict__ o1,
                                                  ushort* __restrict__ o2, ushort* __restrict__ o3,
                                                  float* __restrict__ l0, float* __restrict__ l1,
                                                  float* __restrict__ l2, float* __restrict__ l3) {
    const int p0  = blockIdx.x * 256;
    const int bh  = blockIdx.y;
    const int s   = blockIdx.z;
    const int nsp = gridDim.z;           // 2 or 4
    const int b   = bh / H_, h = bh % H_;
    ushort* opart = (s == 0) ? o0 : (s == 1) ? o1 : (s == 2) ? o2 : o3;
    float*  lpart = (s == 0) ? l0 : (s == 1) ? l1 : (s == 2) ? l2 : l3;
    const int tid  = threadIdx.x;
    const int lane = tid & 63;
    const int wv   = tid >> 6;
    const int half = lane >> 5;     // 0/1
    const int n32  = lane & 31;     // q-column of this lane

    __shared__ __align__(16) ushort KVs[2][2][64][72];

    const size_t hs  = (size_t)P_ * HD_;
    const int    kv0 = s * (P_ / nsp);
    const ushort* qg = qkv + ((size_t)(0 * B_ + b) * H_ + h) * hs + (size_t)(p0 + wv * 64) * HD_;
    const ushort* kg = qkv + ((size_t)(1 * B_ + b) * H_ + h) * hs + (size_t)kv0 * HD_;
    const ushort* vg = qkv + ((size_t)(2 * B_ + b) * H_ + h) * hs + (size_t)kv0 * HD_;

    short8 aq[2][4];
#pragma unroll
    for (int qs2 = 0; qs2 < 2; qs2++)
#pragma unroll
        for (int ks2 = 0; ks2 < 4; ks2++)
            aq[qs2][ks2] = *(const short8*)(qg + (size_t)(qs2 * 32 + n32) * HD_ + ks2 * 16 + half * 8);

    float lsum[2] = {0.f, 0.f};
    f32x16 oaccT[2][2];                  // [qsub][ntd]
#pragma unroll
    for (int q2 = 0; q2 < 2; q2++)
#pragma unroll
        for (int nt = 0; nt < 2; nt++)
#pragma unroll
            for (int r = 0; r < 16; r++) oaccT[q2][nt][r] = 0.f;

    const int kr = tid >> 3, kc8 = tid & 7;
    const int krs = swap23(kr);
    const int vd = tid & 63,  vkh = tid >> 6;

    uint4  kpre[2];
    ushort vpre[16];
    auto load_tile = [&](int kt) {
        const ushort* kg_t = kg + (size_t)kt * 64 * HD_;
        const ushort* vg_t = vg + (size_t)kt * 64 * HD_;
        kpre[0] = *(const uint4*)(kg_t + (size_t)kr * HD_ + kc8 * 8);
        kpre[1] = *(const uint4*)(kg_t + (size_t)(kr + 32) * HD_ + kc8 * 8);
#pragma unroll
        for (int j = 0; j < 16; j++)
            vpre[j] = vg_t[(size_t)(vkh * 16 + j) * HD_ + vd];
    };
    auto stage = [&](int buf) {
        *(uint4*)&KVs[buf][0][krs][kc8 * 8]      = kpre[0];
        *(uint4*)&KVs[buf][0][krs + 32][kc8 * 8] = kpre[1];
        *(short8*)&KVs[buf][1][vd][vkh * 16]     = *(short8*)&vpre[0];
        *(short8*)&KVs[buf][1][vd][vkh * 16 + 8] = *(short8*)&vpre[8];
    };

    load_tile(0);
    stage(0);
    __syncthreads();

    const int NT = (P_ / 64) / nsp;      // 8 (nsp=4) or 16 (nsp=2) — even
    int cur = 0;
    for (int kt = 0; kt < NT; kt++) {
        const bool more = (kt + 1 < NT);
        if (more) load_tile(kt + 1);

        ushort (*Ks)[72] = KVs[cur][0];
        ushort (*Vs)[72] = KVs[cur][1];

#pragma unroll
        for (int nt = 0; nt < 2; nt++) {
#pragma unroll
            for (int q2 = 0; q2 < 2; q2++) {
                f32x16 sc;
#pragma unroll
                for (int r = 0; r < 16; r++) sc[r] = 0.f;
                __builtin_amdgcn_s_setprio(1);
#pragma unroll
                for (int ks2 = 0; ks2 < 4; ks2++) {
                    short8 kb2 = *(const short8*)&Ks[nt * 32 + n32][ks2 * 16 + half * 8];
                    sc = __builtin_amdgcn_mfma_f32_32x32x16_bf16(kb2, aq[q2][ks2], sc, 0, 0, 0);
                }
                __builtin_amdgcn_s_setprio(0);
                float p[16];
#pragma unroll
                for (int r = 0; r < 16; r++) {
                    p[r] = __builtin_amdgcn_exp2f(sc[r]);
                    lsum[q2] += p[r];
                }
                unsigned w[8];
#pragma unroll
                for (int i = 0; i < 8; i++) w[i] = cvtpk(p[2 * i], p[2 * i + 1]);
                __builtin_amdgcn_s_setprio(1);
#pragma unroll
                for (int kp2 = 0; kp2 < 2; kp2++) {
                    u32x4 t = {w[kp2 * 4 + 0], w[kp2 * 4 + 1], w[kp2 * 4 + 2], w[kp2 * 4 + 3]};
                    short8 pb = __builtin_bit_cast(short8, t);
                    const int kstep = nt * 2 + kp2;
#pragma unroll
                    for (int ntd = 0; ntd < 2; ntd++) {
                        short8 av = *(const short8*)&Vs[ntd * 32 + n32][kstep * 16 + half * 8];
                        oaccT[q2][ntd] = __builtin_amdgcn_mfma_f32_32x32x16_bf16(av, pb, oaccT[q2][ntd], 0, 0, 0);
                    }
                }
                __builtin_amdgcn_s_setprio(0);
            }
        }

        if (more) {
            stage(cur ^ 1);
            __syncthreads();
            cur ^= 1;
        }
    }

#pragma unroll
    for (int q2 = 0; q2 < 2; q2++)
        lsum[q2] += __shfl_xor(lsum[q2], 32, 64);
    if (lane < 32) {
        lpart[(size_t)bh * P_ + p0 + wv * 64 +  0 + lane] = lsum[0];
        lpart[(size_t)bh * P_ + p0 + wv * 64 + 32 + lane] = lsum[1];
    }

    float* scr = (float*)&KVs[0][0][0][0] + wv * 1152;
#pragma unroll
    for (int q2 = 0; q2 < 2; q2++) {
#pragma unroll
        for (int ntd = 0; ntd < 2; ntd++) {
#pragma unroll
            for (int r = 0; r < 16; r++)
                scr[n32 * 36 + (r & 3) + 8 * (r >> 2) + 4 * half] = oaccT[q2][ntd][r];
#pragma unroll
            for (int i = 0; i < 4; i++) {
                int ql = i * 8 + (lane >> 3);
                int c4 = lane & 7;
                float4 v = *(const float4*)&scr[ql * 36 + c4 * 4];
                uint2 pk = {cvtpk(v.x, v.y), cvtpk(v.z, v.w)};
                *(uint2*)(opart + ((size_t)bh * P_ + p0 + wv * 64 + q2 * 32 + ql) * HD_ + ntd * 32 + c4 * 4) = pk;
            }
        }
    }
}

// ===========================================================================
// Kernel 3 (R8-verified): LayerNorm over D=768, fused split-combine of bf16
// partials: v = (sum_s o_s) / (sum_s l_s). Sole owner of normalization.
// ===========================================================================
__global__ __launch_bounds__(256) void ln_o(const ushort* __restrict__ o0,
                                            const ushort* __restrict__ o1,
                                            const ushort* __restrict__ o2,
                                            const ushort* __restrict__ o3,
                                            const float* __restrict__ l0,
                                            const float* __restrict__ l1,
                                            const float* __restrict__ l2,
                                            const float* __restrict__ l3,
                                            const int ns,
                                            ushort* __restrict__ lnb,
                                            const float* __restrict__ osc,
                                            const float* __restrict__ ob) {
    __shared__ float red[4];
    __shared__ float red2[4];
    const int row = blockIdx.x;          // b*P + p
    const int b   = row >> 11;
    const int p   = row & (P_ - 1);
    const int tid = threadIdx.x;

    auto src = [&](int d) {
        int h = d >> 6;
        size_t lr  = (size_t)(b * H_ + h) * P_ + p;
        size_t idx = lr * HD_ + (d & 63);
        float num = bf2f(o0[idx]) + bf2f(o1[idx]);
        float den = l0[lr] + l1[lr];
        if (ns == 4) { num += bf2f(o2[idx]) + bf2f(o3[idx]); den += l2[lr] + l3[lr]; }
        return num / den;
    };
    float v0 = src(tid);
    float v1 = src(tid + 256);
    float v2 = src(tid + 512);
    float s = v0 + v1 + v2;
#pragma unroll
    for (int o = 32; o > 0; o >>= 1) s += __shfl_xor(s, o, 64);
    if ((tid & 63) == 0) red[tid >> 6] = s;
    __syncthreads();
    float mean = (red[0] + red[1] + red[2] + red[3]) * (1.0f / 768.0f);
    float d0 = v0 - mean, d1 = v1 - mean, d2 = v2 - mean;
    float sq = d0 * d0 + d1 * d1 + d2 * d2;
#pragma unroll
    for (int o = 32; o > 0; o >>= 1) sq += __shfl_xor(sq, o, 64);
    if ((tid & 63) == 0) red2[tid >> 6] = sq;
    __syncthreads();
    float var = (red2[0] + red2[1] + red2[2] + red2[3]) * (1.0f / 768.0f);
    float inv = rsqrtf(var + 1e-6f);
    const size_t base = (size_t)row * D_;
    lnb[base + tid]       = f2bf(d0 * inv * osc[tid]       + ob[tid]);
    lnb[base + tid + 256] = f2bf(d1 * inv * osc[tid + 256] + ob[tid + 256]);
    lnb[base + tid + 512] = f2bf(d2 * inv * osc[tid + 512] + ob[tid + 512]);
}

// ===========================================================================
// Kernel 4 (R7-verified config): out = ln_buf(bf16) @ W_out + b_out.
// 64x64 tile, BK=32, 256 thr, single-buffered padded LDS, cvtpk B staging.
// ===========================================================================
__global__ __launch_bounds__(256) void gemm_out_mfma(
        const ushort* __restrict__ a, const float* __restrict__ w,
        const float* __restrict__ bias, float* __restrict__ out) {
    __shared__ __align__(16) ushort As[64][40];
    __shared__ __align__(16) ushort Bs[64][40];

    const int tid  = threadIdx.x;
    const int lane = tid & 63;
    const int wv   = tid >> 6;
    const int quad = lane >> 4;
    const int col  = lane & 15;
    const int wr   = (wv >> 1) * 32;
    const int wc   = (wv & 1) * 32;
    const int rowBase = blockIdx.y * 64;
    const int colBase = blockIdx.x * 64;

    const int am  = tid >> 2, ac8 = tid & 3;
    const int nB  = tid & 63, kq = tid >> 6;

    uint4 apre;
    float bpre[8];
    auto load_tile = [&](int kt) {
        const int k0 = kt * 32;
        apre = *(const uint4*)(a + (size_t)(rowBase + am) * D_ + k0 + ac8 * 8);
#pragma unroll
        for (int j = 0; j < 8; j++)
            bpre[j] = w[(size_t)(k0 + kq * 8 + j) * D_ + colBase + nB];
    };

    f32x4 acc[2][2];
#pragma unroll
    for (int i = 0; i < 2; i++)
#pragma unroll
        for (int j = 0; j < 2; j++) acc[i][j] = (f32x4){0.f, 0.f, 0.f, 0.f};

    load_tile(0);
    const int NT = D_ / 32;
    for (int kt = 0; kt < NT; kt++) {
        __syncthreads();
        *(uint4*)&As[am][ac8 * 8] = apre;
        {
            u32x4 bb;
#pragma unroll
            for (int j = 0; j < 4; j++) bb[j] = cvtpk(bpre[2 * j], bpre[2 * j + 1]);
            *(u32x4*)&Bs[nB][kq * 8] = bb;
        }
        __syncthreads();
        if (kt + 1 < NT) load_tile(kt + 1);

        short8 af[2], bf[2];
#pragma unroll
        for (int mt = 0; mt < 2; mt++) af[mt] = *(const short8*)&As[wr + mt * 16 + col][quad * 8];
#pragma unroll
        for (int nt = 0; nt < 2; nt++) bf[nt] = *(const short8*)&Bs[wc + nt * 16 + col][quad * 8];
#pragma unroll
        for (int mt = 0; mt < 2; mt++)
#pragma unroll
            for (int nt = 0; nt < 2; nt++)
                acc[mt][nt] = __builtin_amdgcn_mfma_f32_16x16x32_bf16(af[mt], bf[nt], acc[mt][nt], 0, 0, 0);
    }

    float b2[2];
#pragma unroll
    for (int nt = 0; nt < 2; nt++) b2[nt] = bias[colBase + wc + nt * 16 + col];
#pragma unroll
    for (int mt = 0; mt < 2; mt++) {
#pragma unroll
        for (int r = 0; r < 4; r++) {
            int m = rowBase + wr + mt * 16 + quad * 4 + r;
            float* dst = out + (size_t)m * D_ + colBase + wc;
#pragma unroll
            for (int nt = 0; nt < 2; nt++)
                dst[nt * 16 + col] = acc[mt][nt][r] + b2[nt];
        }
    }
}

// ---------------------------------------------------------------------------
extern "C" void kernel_launch(void* const* d_in, const int* in_sizes, int n_in,
                              void* d_out, int out_size, void* d_ws, size_t ws_size,
                              hipStream_t stream) {
    const float* x    = (const float*)d_in[0];
    const float* Wqkv = (const float*)d_in[1];
    const float* qs   = (const float*)d_in[2];
    const float* qb   = (const float*)d_in[3];
    const float* ks   = (const float*)d_in[4];
    const float* kb   = (const float*)d_in[5];
    const float* osc  = (const float*)d_in[6];
    const float* ob   = (const float*)d_in[7];
    const float* Wout = (const float*)d_in[8];
    const float* bout = (const float*)d_in[9];
    float* out = (float*)d_out;

    // Workspace: qkv bf16 18.9MB | (nsp-1) bf16 O-partials | nsp fp32 l.
    // Last O-partial lives in d_out.
    ushort* qkv = (ushort*)d_ws;
    const size_t qkvE = (size_t)3 * B_ * H_ * P_ * HD_;
    const size_t oE   = (size_t)B_ * H_ * P_ * HD_;
    const size_t lE   = (size_t)B_ * H_ * P_;
    ushort* obase = qkv + qkvE;
    const size_t need4 = (qkvE + 3 * oE) * sizeof(ushort) + 4 * lE * sizeof(float);
    const int nsp = (ws_size >= need4) ? 4 : 2;
    ushort* op[4];
    float* lbase;
    if (nsp == 4) {
        op[0] = obase; op[1] = obase + oE; op[2] = obase + 2 * oE; op[3] = (ushort*)out;
        lbase = (float*)(obase + 3 * oE);
    } else {
        op[0] = obase; op[1] = (ushort*)out; op[2] = obase; op[3] = obase;
        lbase = (float*)(obase + oE);
    }
    float* lp[4] = {lbase, lbase + lE, lbase + 2 * lE, lbase + 3 * lE};
    ushort* ln_buf = qkv;   // overlays dead q-region after attention

    gemm_qkv_mfma<<<dim3(N1_ / 128, M_ / 128), 512, 0, stream>>>(x, Wqkv, qs, qb, ks, kb, qkv);
    attn_split<<<dim3(P_ / 256, B_ * H_, nsp), 256, 0, stream>>>(
        qkv, op[0], op[1], op[2], op[3], lp[0], lp[1], lp[2], lp[3]);
    ln_o<<<dim3(M_), 256, 0, stream>>>(
        op[0], op[1], op[2], op[3], lp[0], lp[1], lp[2], lp[3], nsp, ln_buf, osc, ob);
    gemm_out_mfma<<<dim3(D_ / 64, M_ / 64), 256, 0, stream>>>(ln_buf, Wout, bout, out);
}

// Round 15
// 183.978 us; speedup vs baseline: 1.2725x; 1.0732x over previous
//
#include <hip/hip_runtime.h>
#include <hip/hip_bf16.h>

// Problem constants (B=2, P=2048, D=768, H=12, hd=64)
#define B_  2
#define P_  2048
#define D_  768
#define H_  12
#define HD_ 64
#define M_  (B_ * P_)   // 4096
#define N1_ (3 * D_)    // 2304

typedef __attribute__((ext_vector_type(8))) short short8;    // 8 bf16 (4 VGPRs)
typedef __attribute__((ext_vector_type(4))) float f32x4;     // 16x16 MFMA acc
typedef __attribute__((ext_vector_type(16))) float f32x16;   // 32x32 MFMA acc
typedef __attribute__((ext_vector_type(4))) unsigned u32x4;
typedef unsigned short ushort;

__device__ __forceinline__ ushort f2bf(float f) {
    unsigned u = __float_as_uint(f);
    u += 0x7fffu + ((u >> 16) & 1u);   // RNE
    return (ushort)(u >> 16);
}

// Pack 2 floats -> 1 dword of 2x bf16 (lo=a, hi=b), RNE. HW-verified (r5/r6).
__device__ __forceinline__ unsigned cvtpk(float a, float b) {
    unsigned r;
    asm("v_cvt_pk_bf16_f32 %0, %1, %2" : "=v"(r) : "v"(a), "v"(b));
    return r;
}

__device__ __forceinline__ float bf2f(ushort u) {
    return __uint_as_float((unsigned)u << 16);
}

// Swap bits 2 and 3 of a slot index (involution) — attn K staging permutation.
// Only touches bits 2-3, so swap23(32+r) = 32 + swap23(r).
__device__ __forceinline__ int swap23(int s) {
    return (s & ~12) | ((s & 4) << 1) | ((s & 8) >> 1);
}

// Q pre-scale: hd^-0.5 * log2(e) — attn uses exp2 directly.
#define QSC_ (0.125f * 1.44269504088896340736f)

// ===========================================================================
// Kernel 1 (R7-verified config): qkv = x @ W_qkv + fused per-head QK-LN.
// 128x128 tile, BK=32, 512 thr / 8 waves, single-buffered padded LDS,
// cvtpk staging. This structure measured best across R8/R9/R12 alternatives.
// ===========================================================================
__global__ __launch_bounds__(512) void gemm_qkv_mfma(
        const float* __restrict__ x, const float* __restrict__ w,
        const float* __restrict__ qs, const float* __restrict__ qb,
        const float* __restrict__ ks, const float* __restrict__ kb,
        ushort* __restrict__ qkv) {
    __shared__ __align__(16) ushort As[128][40];
    __shared__ __align__(16) ushort Bs[128][40];

    const int tid  = threadIdx.x;
    const int lane = tid & 63;
    const int wv   = tid >> 6;            // 0..7
    const int quad = lane >> 4;
    const int col  = lane & 15;
    const int wr   = (wv >> 1) * 32;
    const int wc   = (wv & 1) * 64;
    const int rowBase = blockIdx.y * 128;
    const int colBase = blockIdx.x * 128;

    const int am0 = tid >> 3, ac4 = tid & 7;
    const int nB  = tid & 127, kq = tid >> 7;

    float4 apre[2];
    float  bpre[8];
    auto load_tile = [&](int kt) {
        const int k0 = kt * 32;
        apre[0] = *(const float4*)(x + (size_t)(rowBase + am0) * D_ + k0 + ac4 * 4);
        apre[1] = *(const float4*)(x + (size_t)(rowBase + am0 + 64) * D_ + k0 + ac4 * 4);
#pragma unroll
        for (int j = 0; j < 8; j++)
            bpre[j] = w[(size_t)(k0 + kq * 8 + j) * N1_ + colBase + nB];
    };

    f32x4 acc[2][4];
#pragma unroll
    for (int i = 0; i < 2; i++)
#pragma unroll
        for (int j = 0; j < 4; j++) acc[i][j] = (f32x4){0.f, 0.f, 0.f, 0.f};

    load_tile(0);
    const int NT = D_ / 32;
    for (int kt = 0; kt < NT; kt++) {
        __syncthreads();
        {
            uint2 a0 = {cvtpk(apre[0].x, apre[0].y), cvtpk(apre[0].z, apre[0].w)};
            uint2 a1 = {cvtpk(apre[1].x, apre[1].y), cvtpk(apre[1].z, apre[1].w)};
            *(uint2*)&As[am0][ac4 * 4]      = a0;
            *(uint2*)&As[am0 + 64][ac4 * 4] = a1;
            u32x4 bb;
#pragma unroll
            for (int j = 0; j < 4; j++) bb[j] = cvtpk(bpre[2 * j], bpre[2 * j + 1]);
            *(u32x4*)&Bs[nB][kq * 8] = bb;
        }
        __syncthreads();
        if (kt + 1 < NT) load_tile(kt + 1);

        short8 af[2], bf[4];
#pragma unroll
        for (int mt = 0; mt < 2; mt++) af[mt] = *(const short8*)&As[wr + mt * 16 + col][quad * 8];
#pragma unroll
        for (int nt = 0; nt < 4; nt++) bf[nt] = *(const short8*)&Bs[wc + nt * 16 + col][quad * 8];
#pragma unroll
        for (int mt = 0; mt < 2; mt++)
#pragma unroll
            for (int nt = 0; nt < 4; nt++)
                acc[mt][nt] = __builtin_amdgcn_mfma_f32_16x16x32_bf16(af[mt], bf[nt], acc[mt][nt], 0, 0, 0);
    }

    const int comp = colBase / D_;
    const int rem  = colBase + wc - comp * D_;
    const int h    = rem >> 6;
    float sc4[4] = {0, 0, 0, 0}, bi4[4] = {0, 0, 0, 0};
    if (comp == 0) {
#pragma unroll
        for (int nt = 0; nt < 4; nt++) { sc4[nt] = qs[nt * 16 + col]; bi4[nt] = qb[nt * 16 + col]; }
    } else if (comp == 1) {
#pragma unroll
        for (int nt = 0; nt < 4; nt++) { sc4[nt] = ks[nt * 16 + col]; bi4[nt] = kb[nt * 16 + col]; }
    }

#pragma unroll
    for (int mt = 0; mt < 2; mt++) {
#pragma unroll
        for (int r = 0; r < 4; r++) {
            int m  = rowBase + wr + mt * 16 + quad * 4 + r;
            int bb = m >> 11;
            int p  = m & 2047;
            float v0 = acc[mt][0][r], v1 = acc[mt][1][r], v2 = acc[mt][2][r], v3 = acc[mt][3][r];
            if (comp < 2) {
                float s = v0 + v1 + v2 + v3;
#pragma unroll
                for (int off = 1; off < 16; off <<= 1) s += __shfl_xor(s, off, 64);
                float mean = s * (1.0f / 64.0f);
                float d0 = v0 - mean, d1 = v1 - mean, d2 = v2 - mean, d3 = v3 - mean;
                float sq = d0 * d0 + d1 * d1 + d2 * d2 + d3 * d3;
#pragma unroll
                for (int off = 1; off < 16; off <<= 1) sq += __shfl_xor(sq, off, 64);
                float inv = rsqrtf(sq * (1.0f / 64.0f) + 1e-6f);
                v0 = d0 * inv * sc4[0] + bi4[0];
                v1 = d1 * inv * sc4[1] + bi4[1];
                v2 = d2 * inv * sc4[2] + bi4[2];
                v3 = d3 * inv * sc4[3] + bi4[3];
                if (comp == 0) { v0 *= QSC_; v1 *= QSC_; v2 *= QSC_; v3 *= QSC_; }
            }
            size_t base = ((((size_t)comp * B_ + bb) * H_ + h) * P_ + p) * HD_;
            qkv[base +  0 + col] = f2bf(v0);
            qkv[base + 16 + col] = f2bf(v1);
            qkv[base + 32 + col] = f2bf(v2);
            qkv[base + 48 + col] = f2bf(v3);
        }
    }
}

// ===========================================================================
// Kernel 2 (R14): flash attention, 8 waves x 32 q = 256 q per block,
// 512 threads. Same 256-q K/V staging amortization as R11 but with lean
// R7-style per-wave state (~72 VGPR) -> ~24 waves/CU resident (vs 12).
// Swapped QK^T + swap23 staging + exp2 softmax + in-register P + setprio +
// bf16 partial-O. Double-buffered K/V LDS, one barrier per 64-key tile.
// Staging (512 thr): K = 1 uint4/thread (kr=tid>>3 covers 64 rows);
// V = 8 scalar loads/thread (vkh=tid>>6 in 0..7).
// Epilogue scratch spans BOTH LDS buffers (8 x 4.6KB = 36.9KB) -> one
// __syncthreads() before the epilogue closes the cross-wave hazard.
// ===========================================================================
__global__ __launch_bounds__(512) void attn_split(const ushort* __restrict__ qkv,
                                                  ushort* __restrict__ o0, ushort* __restrict__ o1,
                                                  ushort* __restrict__ o2, ushort* __restrict__ o3,
                                                  float* __restrict__ l0, float* __restrict__ l1,
                                                  float* __restrict__ l2, float* __restrict__ l3) {
    const int p0  = blockIdx.x * 256;
    const int bh  = blockIdx.y;
    const int s   = blockIdx.z;
    const int nsp = gridDim.z;           // 2 or 4
    const int b   = bh / H_, h = bh % H_;
    ushort* opart = (s == 0) ? o0 : (s == 1) ? o1 : (s == 2) ? o2 : o3;
    float*  lpart = (s == 0) ? l0 : (s == 1) ? l1 : (s == 2) ? l2 : l3;
    const int tid  = threadIdx.x;
    const int lane = tid & 63;
    const int wv   = tid >> 6;      // 0..7
    const int half = lane >> 5;     // 0/1
    const int n32  = lane & 31;     // q-column of this lane

    __shared__ __align__(16) ushort KVs[2][2][64][72];

    const size_t hs  = (size_t)P_ * HD_;
    const int    kv0 = s * (P_ / nsp);
    const ushort* qg = qkv + ((size_t)(0 * B_ + b) * H_ + h) * hs + (size_t)(p0 + wv * 32) * HD_;
    const ushort* kg = qkv + ((size_t)(1 * B_ + b) * H_ + h) * hs + (size_t)kv0 * HD_;
    const ushort* vg = qkv + ((size_t)(2 * B_ + b) * H_ + h) * hs + (size_t)kv0 * HD_;

    // Q fragments (B-operand of swapped QK): B[k=8*half+j][n=q=n32].
    short8 aq[4];
#pragma unroll
    for (int ks2 = 0; ks2 < 4; ks2++)
        aq[ks2] = *(const short8*)(qg + (size_t)n32 * HD_ + ks2 * 16 + half * 8);

    float lsum = 0.f;
    f32x16 oaccT[2];
#pragma unroll
    for (int nt = 0; nt < 2; nt++)
#pragma unroll
        for (int r = 0; r < 16; r++) oaccT[nt][r] = 0.f;

    // Staging (512 threads): K rows 0..63 (one uint4 each); V dims 0..63 x 8 keys.
    const int kr = tid >> 3, kc8 = tid & 7;
    const int krs = swap23(kr);
    const int vd = tid & 63,  vkh = tid >> 6;   // 0..7

    uint4  kpre;
    ushort vpre[8];
    auto load_tile = [&](int kt) {
        const ushort* kg_t = kg + (size_t)kt * 64 * HD_;
        const ushort* vg_t = vg + (size_t)kt * 64 * HD_;
        kpre = *(const uint4*)(kg_t + (size_t)kr * HD_ + kc8 * 8);
#pragma unroll
        for (int j = 0; j < 8; j++)
            vpre[j] = vg_t[(size_t)(vkh * 8 + j) * HD_ + vd];
    };
    auto stage = [&](int buf) {
        *(uint4*)&KVs[buf][0][krs][kc8 * 8] = kpre;
        *(short8*)&KVs[buf][1][vd][vkh * 8] = *(short8*)&vpre[0];
    };

    load_tile(0);
    stage(0);
    __syncthreads();

    const int NT = (P_ / 64) / nsp;      // 8 (nsp=4) or 16 (nsp=2)
    int cur = 0;
    for (int kt = 0; kt < NT; kt++) {
        const bool more = (kt + 1 < NT);
        if (more) load_tile(kt + 1);

        ushort (*Ks)[72] = KVs[cur][0];
        ushort (*Vs)[72] = KVs[cur][1];

#pragma unroll
        for (int nt = 0; nt < 2; nt++) {
            f32x16 sc;
#pragma unroll
            for (int r = 0; r < 16; r++) sc[r] = 0.f;
            __builtin_amdgcn_s_setprio(1);
#pragma unroll
            for (int ks2 = 0; ks2 < 4; ks2++) {
                short8 kb2 = *(const short8*)&Ks[nt * 32 + n32][ks2 * 16 + half * 8];
                sc = __builtin_amdgcn_mfma_f32_32x32x16_bf16(kb2, aq[ks2], sc, 0, 0, 0);
            }
            __builtin_amdgcn_s_setprio(0);
            float p[16];
#pragma unroll
            for (int r = 0; r < 16; r++) {
                p[r] = __builtin_amdgcn_exp2f(sc[r]);
                lsum += p[r];
            }
            unsigned w[8];
#pragma unroll
            for (int i = 0; i < 8; i++) w[i] = cvtpk(p[2 * i], p[2 * i + 1]);
            __builtin_amdgcn_s_setprio(1);
#pragma unroll
            for (int kp2 = 0; kp2 < 2; kp2++) {
                u32x4 t = {w[kp2 * 4 + 0], w[kp2 * 4 + 1], w[kp2 * 4 + 2], w[kp2 * 4 + 3]};
                short8 pb = __builtin_bit_cast(short8, t);
                const int kstep = nt * 2 + kp2;
#pragma unroll
                for (int ntd = 0; ntd < 2; ntd++) {
                    short8 av = *(const short8*)&Vs[ntd * 32 + n32][kstep * 16 + half * 8];
                    oaccT[ntd] = __builtin_amdgcn_mfma_f32_32x32x16_bf16(av, pb, oaccT[ntd], 0, 0, 0);
                }
            }
            __builtin_amdgcn_s_setprio(0);
        }

        if (more) {
            stage(cur ^ 1);
            __syncthreads();
            cur ^= 1;
        }
    }

    // Row-sum: lane-local accumulation + one cross-half exchange.
    lsum += __shfl_xor(lsum, 32, 64);
    if (lane < 32)
        lpart[(size_t)bh * P_ + p0 + wv * 32 + lane] = lsum;

    // All waves done with K/V reads before scratch clobbers both buffers.
    __syncthreads();
    float* scr = (float*)&KVs[0][0][0][0] + wv * 1152;   // 8 x 4.6KB = full 36.9KB
#pragma unroll
    for (int ntd = 0; ntd < 2; ntd++) {
#pragma unroll
        for (int r = 0; r < 16; r++)
            scr[n32 * 36 + (r & 3) + 8 * (r >> 2) + 4 * half] = oaccT[ntd][r];
        // In-wave DS ordering: writes above complete before reads below.
#pragma unroll
        for (int i = 0; i < 4; i++) {
            int ql = i * 8 + (lane >> 3);
            int c4 = lane & 7;
            float4 v = *(const float4*)&scr[ql * 36 + c4 * 4];
            uint2 pk = {cvtpk(v.x, v.y), cvtpk(v.z, v.w)};
            *(uint2*)(opart + ((size_t)bh * P_ + p0 + wv * 32 + ql) * HD_ + ntd * 32 + c4 * 4) = pk;
        }
    }
}

// ===========================================================================
// Kernel 3 (R8-verified): LayerNorm over D=768, fused split-combine of bf16
// partials: v = (sum_s o_s) / (sum_s l_s). Sole owner of normalization.
// ===========================================================================
__global__ __launch_bounds__(256) void ln_o(const ushort* __restrict__ o0,
                                            const ushort* __restrict__ o1,
                                            const ushort* __restrict__ o2,
                                            const ushort* __restrict__ o3,
                                            const float* __restrict__ l0,
                                            const float* __restrict__ l1,
                                            const float* __restrict__ l2,
                                            const float* __restrict__ l3,
                                            const int ns,
                                            ushort* __restrict__ lnb,
                                            const float* __restrict__ osc,
                                            const float* __restrict__ ob) {
    __shared__ float red[4];
    __shared__ float red2[4];
    const int row = blockIdx.x;          // b*P + p
    const int b   = row >> 11;
    const int p   = row & (P_ - 1);
    const int tid = threadIdx.x;

    auto src = [&](int d) {
        int h = d >> 6;
        size_t lr  = (size_t)(b * H_ + h) * P_ + p;
        size_t idx = lr * HD_ + (d & 63);
        float num = bf2f(o0[idx]) + bf2f(o1[idx]);
        float den = l0[lr] + l1[lr];
        if (ns == 4) { num += bf2f(o2[idx]) + bf2f(o3[idx]); den += l2[lr] + l3[lr]; }
        return num / den;
    };
    float v0 = src(tid);
    float v1 = src(tid + 256);
    float v2 = src(tid + 512);
    float s = v0 + v1 + v2;
#pragma unroll
    for (int o = 32; o > 0; o >>= 1) s += __shfl_xor(s, o, 64);
    if ((tid & 63) == 0) red[tid >> 6] = s;
    __syncthreads();
    float mean = (red[0] + red[1] + red[2] + red[3]) * (1.0f / 768.0f);
    float d0 = v0 - mean, d1 = v1 - mean, d2 = v2 - mean;
    float sq = d0 * d0 + d1 * d1 + d2 * d2;
#pragma unroll
    for (int o = 32; o > 0; o >>= 1) sq += __shfl_xor(sq, o, 64);
    if ((tid & 63) == 0) red2[tid >> 6] = sq;
    __syncthreads();
    float var = (red2[0] + red2[1] + red2[2] + red2[3]) * (1.0f / 768.0f);
    float inv = rsqrtf(var + 1e-6f);
    const size_t base = (size_t)row * D_;
    lnb[base + tid]       = f2bf(d0 * inv * osc[tid]       + ob[tid]);
    lnb[base + tid + 256] = f2bf(d1 * inv * osc[tid + 256] + ob[tid + 256]);
    lnb[base + tid + 512] = f2bf(d2 * inv * osc[tid + 512] + ob[tid + 512]);
}

// ===========================================================================
// Kernel 4 (R7-verified config): out = ln_buf(bf16) @ W_out + b_out.
// 64x64 tile, BK=32, 256 thr, single-buffered padded LDS, cvtpk B staging.
// ===========================================================================
__global__ __launch_bounds__(256) void gemm_out_mfma(
        const ushort* __restrict__ a, const float* __restrict__ w,
        const float* __restrict__ bias, float* __restrict__ out) {
    __shared__ __align__(16) ushort As[64][40];
    __shared__ __align__(16) ushort Bs[64][40];

    const int tid  = threadIdx.x;
    const int lane = tid & 63;
    const int wv   = tid >> 6;
    const int quad = lane >> 4;
    const int col  = lane & 15;
    const int wr   = (wv >> 1) * 32;
    const int wc   = (wv & 1) * 32;
    const int rowBase = blockIdx.y * 64;
    const int colBase = blockIdx.x * 64;

    const int am  = tid >> 2, ac8 = tid & 3;
    const int nB  = tid & 63, kq = tid >> 6;

    uint4 apre;
    float bpre[8];
    auto load_tile = [&](int kt) {
        const int k0 = kt * 32;
        apre = *(const uint4*)(a + (size_t)(rowBase + am) * D_ + k0 + ac8 * 8);
#pragma unroll
        for (int j = 0; j < 8; j++)
            bpre[j] = w[(size_t)(k0 + kq * 8 + j) * D_ + colBase + nB];
    };

    f32x4 acc[2][2];
#pragma unroll
    for (int i = 0; i < 2; i++)
#pragma unroll
        for (int j = 0; j < 2; j++) acc[i][j] = (f32x4){0.f, 0.f, 0.f, 0.f};

    load_tile(0);
    const int NT = D_ / 32;
    for (int kt = 0; kt < NT; kt++) {
        __syncthreads();
        *(uint4*)&As[am][ac8 * 8] = apre;
        {
            u32x4 bb;
#pragma unroll
            for (int j = 0; j < 4; j++) bb[j] = cvtpk(bpre[2 * j], bpre[2 * j + 1]);
            *(u32x4*)&Bs[nB][kq * 8] = bb;
        }
        __syncthreads();
        if (kt + 1 < NT) load_tile(kt + 1);

        short8 af[2], bf[2];
#pragma unroll
        for (int mt = 0; mt < 2; mt++) af[mt] = *(const short8*)&As[wr + mt * 16 + col][quad * 8];
#pragma unroll
        for (int nt = 0; nt < 2; nt++) bf[nt] = *(const short8*)&Bs[wc + nt * 16 + col][quad * 8];
#pragma unroll
        for (int mt = 0; mt < 2; mt++)
#pragma unroll
            for (int nt = 0; nt < 2; nt++)
                acc[mt][nt] = __builtin_amdgcn_mfma_f32_16x16x32_bf16(af[mt], bf[nt], acc[mt][nt], 0, 0, 0);
    }

    float b2[2];
#pragma unroll
    for (int nt = 0; nt < 2; nt++) b2[nt] = bias[colBase + wc + nt * 16 + col];
#pragma unroll
    for (int mt = 0; mt < 2; mt++) {
#pragma unroll
        for (int r = 0; r < 4; r++) {
            int m = rowBase + wr + mt * 16 + quad * 4 + r;
            float* dst = out + (size_t)m * D_ + colBase + wc;
#pragma unroll
            for (int nt = 0; nt < 2; nt++)
                dst[nt * 16 + col] = acc[mt][nt][r] + b2[nt];
        }
    }
}

// ---------------------------------------------------------------------------
extern "C" void kernel_launch(void* const* d_in, const int* in_sizes, int n_in,
                              void* d_out, int out_size, void* d_ws, size_t ws_size,
                              hipStream_t stream) {
    const float* x    = (const float*)d_in[0];
    const float* Wqkv = (const float*)d_in[1];
    const float* qs   = (const float*)d_in[2];
    const float* qb   = (const float*)d_in[3];
    const float* ks   = (const float*)d_in[4];
    const float* kb   = (const float*)d_in[5];
    const float* osc  = (const float*)d_in[6];
    const float* ob   = (const float*)d_in[7];
    const float* Wout = (const float*)d_in[8];
    const float* bout = (const float*)d_in[9];
    float* out = (float*)d_out;

    // Workspace: qkv bf16 18.9MB | (nsp-1) bf16 O-partials | nsp fp32 l.
    // Last O-partial lives in d_out.
    ushort* qkv = (ushort*)d_ws;
    const size_t qkvE = (size_t)3 * B_ * H_ * P_ * HD_;
    const size_t oE   = (size_t)B_ * H_ * P_ * HD_;
    const size_t lE   = (size_t)B_ * H_ * P_;
    ushort* obase = qkv + qkvE;
    const size_t need4 = (qkvE + 3 * oE) * sizeof(ushort) + 4 * lE * sizeof(float);
    const int nsp = (ws_size >= need4) ? 4 : 2;
    ushort* op[4];
    float* lbase;
    if (nsp == 4) {
        op[0] = obase; op[1] = obase + oE; op[2] = obase + 2 * oE; op[3] = (ushort*)out;
        lbase = (float*)(obase + 3 * oE);
    } else {
        op[0] = obase; op[1] = (ushort*)out; op[2] = obase; op[3] = obase;
        lbase = (float*)(obase + oE);
    }
    float* lp[4] = {lbase, lbase + lE, lbase + 2 * lE, lbase + 3 * lE};
    ushort* ln_buf = qkv;   // overlays dead q-region after attention

    gemm_qkv_mfma<<<dim3(N1_ / 128, M_ / 128), 512, 0, stream>>>(x, Wqkv, qs, qb, ks, kb, qkv);
    attn_split<<<dim3(P_ / 256, B_ * H_, nsp), 512, 0, stream>>>(
        qkv, op[0], op[1], op[2], op[3], lp[0], lp[1], lp[2], lp[3]);
    ln_o<<<dim3(M_), 256, 0, stream>>>(
        op[0], op[1], op[2], op[3], lp[0], lp[1], lp[2], lp[3], nsp, ln_buf, osc, ob);
    gemm_out_mfma<<<dim3(D_ / 64, M_ / 64), 256, 0, stream>>>(ln_buf, Wout, bout, out);
}

// Round 16
// 183.089 us; speedup vs baseline: 1.2786x; 1.0049x over previous
//
#include <hip/hip_runtime.h>
#include <hip/hip_bf16.h>

// Problem constants (B=2, P=2048, D=768, H=12, hd=64)
#define B_  2
#define P_  2048
#define D_  768
#define H_  12
#define HD_ 64
#define M_  (B_ * P_)   // 4096
#define N1_ (3 * D_)    // 2304

typedef __attribute__((ext_vector_type(8))) short short8;    // 8 bf16 (4 VGPRs)
typedef __attribute__((ext_vector_type(4))) float f32x4;     // 16x16 MFMA acc
typedef __attribute__((ext_vector_type(16))) float f32x16;   // 32x32 MFMA acc
typedef __attribute__((ext_vector_type(4))) unsigned u32x4;
typedef unsigned short ushort;

__device__ __forceinline__ ushort f2bf(float f) {
    unsigned u = __float_as_uint(f);
    u += 0x7fffu + ((u >> 16) & 1u);   // RNE
    return (ushort)(u >> 16);
}

// Pack 2 floats -> 1 dword of 2x bf16 (lo=a, hi=b), RNE. HW-verified (r5/r6).
__device__ __forceinline__ unsigned cvtpk(float a, float b) {
    unsigned r;
    asm("v_cvt_pk_bf16_f32 %0, %1, %2" : "=v"(r) : "v"(a), "v"(b));
    return r;
}

__device__ __forceinline__ float bf2f(ushort u) {
    return __uint_as_float((unsigned)u << 16);
}

// Swap bits 2 and 3 of a slot index (involution) — attn K staging permutation.
__device__ __forceinline__ int swap23(int s) {
    return (s & ~12) | ((s & 4) << 1) | ((s & 8) >> 1);
}

// Q pre-scale: hd^-0.5 * log2(e) — attn uses exp2 directly.
#define QSC_ (0.125f * 1.44269504088896340736f)

// ===========================================================================
// Kernel 0 (R16): transpose + cast. dst[n][k] = bf16(src[k][n]).
// src is K x N row-major fp32. 64x64 LDS tile, coalesced on both sides.
// One-shot cost; removes the 8-scalar-strided B-gather from both GEMMs'
// 24-step hot loops (512 cache lines/wave/step -> 16).
// ===========================================================================
__global__ __launch_bounds__(256) void precast_wt(const float* __restrict__ src,
                                                  ushort* __restrict__ dst,
                                                  const int K, const int N) {
    __shared__ ushort t[64][65];
    const int k0 = blockIdx.y * 64;
    const int n0 = blockIdx.x * 64;
    const int tid = threadIdx.x;
    const int c  = tid & 63;      // coalesced inner index
    const int r4 = tid >> 6;      // 0..3
#pragma unroll
    for (int j = 0; j < 16; j++) {
        int k = r4 + j * 4;
        t[k][c] = f2bf(src[(size_t)(k0 + k) * N + n0 + c]);
    }
    __syncthreads();
#pragma unroll
    for (int j = 0; j < 16; j++) {
        int n = r4 + j * 4;
        dst[(size_t)(n0 + n) * K + k0 + c] = t[c][n];
    }
}

// ===========================================================================
// Kernel 1 (R16): qkv = x @ W_qkv + fused per-head QK-LN.
// R7-verified structure (128x128, BK=32, 512 thr, single-buffered padded
// LDS); B staging now ONE coalesced uint4 from transposed-bf16 wqt
// (was 8 scalar fp32 loads at 9KB stride). A path / reads / epilogue
// byte-identical to R15.
// ===========================================================================
__global__ __launch_bounds__(512) void gemm_qkv_mfma(
        const float* __restrict__ x, const ushort* __restrict__ wt,
        const float* __restrict__ qs, const float* __restrict__ qb,
        const float* __restrict__ ks, const float* __restrict__ kb,
        ushort* __restrict__ qkv) {
    __shared__ __align__(16) ushort As[128][40];
    __shared__ __align__(16) ushort Bs[128][40];

    const int tid  = threadIdx.x;
    const int lane = tid & 63;
    const int wv   = tid >> 6;            // 0..7
    const int quad = lane >> 4;
    const int col  = lane & 15;
    const int wr   = (wv >> 1) * 32;
    const int wc   = (wv & 1) * 64;
    const int rowBase = blockIdx.y * 128;
    const int colBase = blockIdx.x * 128;

    const int am0 = tid >> 3, ac4 = tid & 7;
    const int nB2 = tid >> 2, kc2 = tid & 3;   // B: n 0..127, 16B k-chunk 0..3

    float4 apre[2];
    uint4  bpre;
    auto load_tile = [&](int kt) {
        const int k0 = kt * 32;
        apre[0] = *(const float4*)(x + (size_t)(rowBase + am0) * D_ + k0 + ac4 * 4);
        apre[1] = *(const float4*)(x + (size_t)(rowBase + am0 + 64) * D_ + k0 + ac4 * 4);
        bpre = *(const uint4*)(wt + (size_t)(colBase + nB2) * D_ + k0 + kc2 * 8);
    };

    f32x4 acc[2][4];
#pragma unroll
    for (int i = 0; i < 2; i++)
#pragma unroll
        for (int j = 0; j < 4; j++) acc[i][j] = (f32x4){0.f, 0.f, 0.f, 0.f};

    load_tile(0);
    const int NT = D_ / 32;
    for (int kt = 0; kt < NT; kt++) {
        __syncthreads();
        {
            uint2 a0 = {cvtpk(apre[0].x, apre[0].y), cvtpk(apre[0].z, apre[0].w)};
            uint2 a1 = {cvtpk(apre[1].x, apre[1].y), cvtpk(apre[1].z, apre[1].w)};
            *(uint2*)&As[am0][ac4 * 4]      = a0;
            *(uint2*)&As[am0 + 64][ac4 * 4] = a1;
            *(uint4*)&Bs[nB2][kc2 * 8]      = bpre;
        }
        __syncthreads();
        if (kt + 1 < NT) load_tile(kt + 1);

        short8 af[2], bf[4];
#pragma unroll
        for (int mt = 0; mt < 2; mt++) af[mt] = *(const short8*)&As[wr + mt * 16 + col][quad * 8];
#pragma unroll
        for (int nt = 0; nt < 4; nt++) bf[nt] = *(const short8*)&Bs[wc + nt * 16 + col][quad * 8];
#pragma unroll
        for (int mt = 0; mt < 2; mt++)
#pragma unroll
            for (int nt = 0; nt < 4; nt++)
                acc[mt][nt] = __builtin_amdgcn_mfma_f32_16x16x32_bf16(af[mt], bf[nt], acc[mt][nt], 0, 0, 0);
    }

    const int comp = colBase / D_;
    const int rem  = colBase + wc - comp * D_;
    const int h    = rem >> 6;
    float sc4[4] = {0, 0, 0, 0}, bi4[4] = {0, 0, 0, 0};
    if (comp == 0) {
#pragma unroll
        for (int nt = 0; nt < 4; nt++) { sc4[nt] = qs[nt * 16 + col]; bi4[nt] = qb[nt * 16 + col]; }
    } else if (comp == 1) {
#pragma unroll
        for (int nt = 0; nt < 4; nt++) { sc4[nt] = ks[nt * 16 + col]; bi4[nt] = kb[nt * 16 + col]; }
    }

#pragma unroll
    for (int mt = 0; mt < 2; mt++) {
#pragma unroll
        for (int r = 0; r < 4; r++) {
            int m  = rowBase + wr + mt * 16 + quad * 4 + r;
            int bb = m >> 11;
            int p  = m & 2047;
            float v0 = acc[mt][0][r], v1 = acc[mt][1][r], v2 = acc[mt][2][r], v3 = acc[mt][3][r];
            if (comp < 2) {
                float s = v0 + v1 + v2 + v3;
#pragma unroll
                for (int off = 1; off < 16; off <<= 1) s += __shfl_xor(s, off, 64);
                float mean = s * (1.0f / 64.0f);
                float d0 = v0 - mean, d1 = v1 - mean, d2 = v2 - mean, d3 = v3 - mean;
                float sq = d0 * d0 + d1 * d1 + d2 * d2 + d3 * d3;
#pragma unroll
                for (int off = 1; off < 16; off <<= 1) sq += __shfl_xor(sq, off, 64);
                float inv = rsqrtf(sq * (1.0f / 64.0f) + 1e-6f);
                v0 = d0 * inv * sc4[0] + bi4[0];
                v1 = d1 * inv * sc4[1] + bi4[1];
                v2 = d2 * inv * sc4[2] + bi4[2];
                v3 = d3 * inv * sc4[3] + bi4[3];
                if (comp == 0) { v0 *= QSC_; v1 *= QSC_; v2 *= QSC_; v3 *= QSC_; }
            }
            size_t base = ((((size_t)comp * B_ + bb) * H_ + h) * P_ + p) * HD_;
            qkv[base +  0 + col] = f2bf(v0);
            qkv[base + 16 + col] = f2bf(v1);
            qkv[base + 32 + col] = f2bf(v2);
            qkv[base + 48 + col] = f2bf(v3);
        }
    }
}

// ===========================================================================
// Kernel 2 (R15-verified): flash attention, 8 waves x 32 q = 256 q per block,
// 512 threads. Swapped QK^T + swap23 + exp2 + in-register P + setprio +
// bf16 partial-O. Double-buffered K/V LDS, one barrier per 64-key tile.
// ===========================================================================
__global__ __launch_bounds__(512) void attn_split(const ushort* __restrict__ qkv,
                                                  ushort* __restrict__ o0, ushort* __restrict__ o1,
                                                  ushort* __restrict__ o2, ushort* __restrict__ o3,
                                                  float* __restrict__ l0, float* __restrict__ l1,
                                                  float* __restrict__ l2, float* __restrict__ l3) {
    const int p0  = blockIdx.x * 256;
    const int bh  = blockIdx.y;
    const int s   = blockIdx.z;
    const int nsp = gridDim.z;           // 2 or 4
    const int b   = bh / H_, h = bh % H_;
    ushort* opart = (s == 0) ? o0 : (s == 1) ? o1 : (s == 2) ? o2 : o3;
    float*  lpart = (s == 0) ? l0 : (s == 1) ? l1 : (s == 2) ? l2 : l3;
    const int tid  = threadIdx.x;
    const int lane = tid & 63;
    const int wv   = tid >> 6;      // 0..7
    const int half = lane >> 5;     // 0/1
    const int n32  = lane & 31;     // q-column of this lane

    __shared__ __align__(16) ushort KVs[2][2][64][72];

    const size_t hs  = (size_t)P_ * HD_;
    const int    kv0 = s * (P_ / nsp);
    const ushort* qg = qkv + ((size_t)(0 * B_ + b) * H_ + h) * hs + (size_t)(p0 + wv * 32) * HD_;
    const ushort* kg = qkv + ((size_t)(1 * B_ + b) * H_ + h) * hs + (size_t)kv0 * HD_;
    const ushort* vg = qkv + ((size_t)(2 * B_ + b) * H_ + h) * hs + (size_t)kv0 * HD_;

    // Q fragments (B-operand of swapped QK): B[k=8*half+j][n=q=n32].
    short8 aq[4];
#pragma unroll
    for (int ks2 = 0; ks2 < 4; ks2++)
        aq[ks2] = *(const short8*)(qg + (size_t)n32 * HD_ + ks2 * 16 + half * 8);

    float lsum = 0.f;
    f32x16 oaccT[2];
#pragma unroll
    for (int nt = 0; nt < 2; nt++)
#pragma unroll
        for (int r = 0; r < 16; r++) oaccT[nt][r] = 0.f;

    // Staging (512 threads): K rows 0..63 (one uint4 each); V dims 0..63 x 8 keys.
    const int kr = tid >> 3, kc8 = tid & 7;
    const int krs = swap23(kr);
    const int vd = tid & 63,  vkh = tid >> 6;   // 0..7

    uint4  kpre;
    ushort vpre[8];
    auto load_tile = [&](int kt) {
        const ushort* kg_t = kg + (size_t)kt * 64 * HD_;
        const ushort* vg_t = vg + (size_t)kt * 64 * HD_;
        kpre = *(const uint4*)(kg_t + (size_t)kr * HD_ + kc8 * 8);
#pragma unroll
        for (int j = 0; j < 8; j++)
            vpre[j] = vg_t[(size_t)(vkh * 8 + j) * HD_ + vd];
    };
    auto stage = [&](int buf) {
        *(uint4*)&KVs[buf][0][krs][kc8 * 8] = kpre;
        *(short8*)&KVs[buf][1][vd][vkh * 8] = *(short8*)&vpre[0];
    };

    load_tile(0);
    stage(0);
    __syncthreads();

    const int NT = (P_ / 64) / nsp;      // 8 (nsp=4) or 16 (nsp=2)
    int cur = 0;
    for (int kt = 0; kt < NT; kt++) {
        const bool more = (kt + 1 < NT);
        if (more) load_tile(kt + 1);

        ushort (*Ks)[72] = KVs[cur][0];
        ushort (*Vs)[72] = KVs[cur][1];

#pragma unroll
        for (int nt = 0; nt < 2; nt++) {
            f32x16 sc;
#pragma unroll
            for (int r = 0; r < 16; r++) sc[r] = 0.f;
            __builtin_amdgcn_s_setprio(1);
#pragma unroll
            for (int ks2 = 0; ks2 < 4; ks2++) {
                short8 kb2 = *(const short8*)&Ks[nt * 32 + n32][ks2 * 16 + half * 8];
                sc = __builtin_amdgcn_mfma_f32_32x32x16_bf16(kb2, aq[ks2], sc, 0, 0, 0);
            }
            __builtin_amdgcn_s_setprio(0);
            float p[16];
#pragma unroll
            for (int r = 0; r < 16; r++) {
                p[r] = __builtin_amdgcn_exp2f(sc[r]);
                lsum += p[r];
            }
            unsigned w[8];
#pragma unroll
            for (int i = 0; i < 8; i++) w[i] = cvtpk(p[2 * i], p[2 * i + 1]);
            __builtin_amdgcn_s_setprio(1);
#pragma unroll
            for (int kp2 = 0; kp2 < 2; kp2++) {
                u32x4 t = {w[kp2 * 4 + 0], w[kp2 * 4 + 1], w[kp2 * 4 + 2], w[kp2 * 4 + 3]};
                short8 pb = __builtin_bit_cast(short8, t);
                const int kstep = nt * 2 + kp2;
#pragma unroll
                for (int ntd = 0; ntd < 2; ntd++) {
                    short8 av = *(const short8*)&Vs[ntd * 32 + n32][kstep * 16 + half * 8];
                    oaccT[ntd] = __builtin_amdgcn_mfma_f32_32x32x16_bf16(av, pb, oaccT[ntd], 0, 0, 0);
                }
            }
            __builtin_amdgcn_s_setprio(0);
        }

        if (more) {
            stage(cur ^ 1);
            __syncthreads();
            cur ^= 1;
        }
    }

    // Row-sum: lane-local accumulation + one cross-half exchange.
    lsum += __shfl_xor(lsum, 32, 64);
    if (lane < 32)
        lpart[(size_t)bh * P_ + p0 + wv * 32 + lane] = lsum;

    // All waves done with K/V reads before scratch clobbers both buffers.
    __syncthreads();
    float* scr = (float*)&KVs[0][0][0][0] + wv * 1152;   // 8 x 4.6KB = full 36.9KB
#pragma unroll
    for (int ntd = 0; ntd < 2; ntd++) {
#pragma unroll
        for (int r = 0; r < 16; r++)
            scr[n32 * 36 + (r & 3) + 8 * (r >> 2) + 4 * half] = oaccT[ntd][r];
        // In-wave DS ordering: writes above complete before reads below.
#pragma unroll
        for (int i = 0; i < 4; i++) {
            int ql = i * 8 + (lane >> 3);
            int c4 = lane & 7;
            float4 v = *(const float4*)&scr[ql * 36 + c4 * 4];
            uint2 pk = {cvtpk(v.x, v.y), cvtpk(v.z, v.w)};
            *(uint2*)(opart + ((size_t)bh * P_ + p0 + wv * 32 + ql) * HD_ + ntd * 32 + c4 * 4) = pk;
        }
    }
}

// ===========================================================================
// Kernel 3 (R8-verified): LayerNorm over D=768, fused split-combine of bf16
// partials: v = (sum_s o_s) / (sum_s l_s). Sole owner of normalization.
// ===========================================================================
__global__ __launch_bounds__(256) void ln_o(const ushort* __restrict__ o0,
                                            const ushort* __restrict__ o1,
                                            const ushort* __restrict__ o2,
                                            const ushort* __restrict__ o3,
                                            const float* __restrict__ l0,
                                            const float* __restrict__ l1,
                                            const float* __restrict__ l2,
                                            const float* __restrict__ l3,
                                            const int ns,
                                            ushort* __restrict__ lnb,
                                            const float* __restrict__ osc,
                                            const float* __restrict__ ob) {
    __shared__ float red[4];
    __shared__ float red2[4];
    const int row = blockIdx.x;          // b*P + p
    const int b   = row >> 11;
    const int p   = row & (P_ - 1);
    const int tid = threadIdx.x;

    auto src = [&](int d) {
        int h = d >> 6;
        size_t lr  = (size_t)(b * H_ + h) * P_ + p;
        size_t idx = lr * HD_ + (d & 63);
        float num = bf2f(o0[idx]) + bf2f(o1[idx]);
        float den = l0[lr] + l1[lr];
        if (ns == 4) { num += bf2f(o2[idx]) + bf2f(o3[idx]); den += l2[lr] + l3[lr]; }
        return num / den;
    };
    float v0 = src(tid);
    float v1 = src(tid + 256);
    float v2 = src(tid + 512);
    float s = v0 + v1 + v2;
#pragma unroll
    for (int o = 32; o > 0; o >>= 1) s += __shfl_xor(s, o, 64);
    if ((tid & 63) == 0) red[tid >> 6] = s;
    __syncthreads();
    float mean = (red[0] + red[1] + red[2] + red[3]) * (1.0f / 768.0f);
    float d0 = v0 - mean, d1 = v1 - mean, d2 = v2 - mean;
    float sq = d0 * d0 + d1 * d1 + d2 * d2;
#pragma unroll
    for (int o = 32; o > 0; o >>= 1) sq += __shfl_xor(sq, o, 64);
    if ((tid & 63) == 0) red2[tid >> 6] = sq;
    __syncthreads();
    float var = (red2[0] + red2[1] + red2[2] + red2[3]) * (1.0f / 768.0f);
    float inv = rsqrtf(var + 1e-6f);
    const size_t base = (size_t)row * D_;
    lnb[base + tid]       = f2bf(d0 * inv * osc[tid]       + ob[tid]);
    lnb[base + tid + 256] = f2bf(d1 * inv * osc[tid + 256] + ob[tid + 256]);
    lnb[base + tid + 512] = f2bf(d2 * inv * osc[tid + 512] + ob[tid + 512]);
}

// ===========================================================================
// Kernel 4 (R16): out = ln_buf(bf16) @ W_out + b_out. R7-verified structure;
// B staging now one coalesced uint4 from transposed-bf16 wot.
// ===========================================================================
__global__ __launch_bounds__(256) void gemm_out_mfma(
        const ushort* __restrict__ a, const ushort* __restrict__ wt,
        const float* __restrict__ bias, float* __restrict__ out) {
    __shared__ __align__(16) ushort As[64][40];
    __shared__ __align__(16) ushort Bs[64][40];

    const int tid  = threadIdx.x;
    const int lane = tid & 63;
    const int wv   = tid >> 6;
    const int quad = lane >> 4;
    const int col  = lane & 15;
    const int wr   = (wv >> 1) * 32;
    const int wc   = (wv & 1) * 32;
    const int rowBase = blockIdx.y * 64;
    const int colBase = blockIdx.x * 64;

    const int am  = tid >> 2, ac8 = tid & 3;
    const int nB2 = tid >> 2, kc2 = tid & 3;   // B: n 0..63, 16B k-chunk 0..3

    uint4 apre, bpre;
    auto load_tile = [&](int kt) {
        const int k0 = kt * 32;
        apre = *(const uint4*)(a  + (size_t)(rowBase + am)  * D_ + k0 + ac8 * 8);
        bpre = *(const uint4*)(wt + (size_t)(colBase + nB2) * D_ + k0 + kc2 * 8);
    };

    f32x4 acc[2][2];
#pragma unroll
    for (int i = 0; i < 2; i++)
#pragma unroll
        for (int j = 0; j < 2; j++) acc[i][j] = (f32x4){0.f, 0.f, 0.f, 0.f};

    load_tile(0);
    const int NT = D_ / 32;
    for (int kt = 0; kt < NT; kt++) {
        __syncthreads();
        *(uint4*)&As[am][ac8 * 8]  = apre;
        *(uint4*)&Bs[nB2][kc2 * 8] = bpre;
        __syncthreads();
        if (kt + 1 < NT) load_tile(kt + 1);

        short8 af[2], bf[2];
#pragma unroll
        for (int mt = 0; mt < 2; mt++) af[mt] = *(const short8*)&As[wr + mt * 16 + col][quad * 8];
#pragma unroll
        for (int nt = 0; nt < 2; nt++) bf[nt] = *(const short8*)&Bs[wc + nt * 16 + col][quad * 8];
#pragma unroll
        for (int mt = 0; mt < 2; mt++)
#pragma unroll
            for (int nt = 0; nt < 2; nt++)
                acc[mt][nt] = __builtin_amdgcn_mfma_f32_16x16x32_bf16(af[mt], bf[nt], acc[mt][nt], 0, 0, 0);
    }

    float b2[2];
#pragma unroll
    for (int nt = 0; nt < 2; nt++) b2[nt] = bias[colBase + wc + nt * 16 + col];
#pragma unroll
    for (int mt = 0; mt < 2; mt++) {
#pragma unroll
        for (int r = 0; r < 4; r++) {
            int m = rowBase + wr + mt * 16 + quad * 4 + r;
            float* dst = out + (size_t)m * D_ + colBase + wc;
#pragma unroll
            for (int nt = 0; nt < 2; nt++)
                dst[nt * 16 + col] = acc[mt][nt][r] + b2[nt];
        }
    }
}

// ---------------------------------------------------------------------------
extern "C" void kernel_launch(void* const* d_in, const int* in_sizes, int n_in,
                              void* d_out, int out_size, void* d_ws, size_t ws_size,
                              hipStream_t stream) {
    const float* x    = (const float*)d_in[0];
    const float* Wqkv = (const float*)d_in[1];
    const float* qs   = (const float*)d_in[2];
    const float* qb   = (const float*)d_in[3];
    const float* ks   = (const float*)d_in[4];
    const float* kb   = (const float*)d_in[5];
    const float* osc  = (const float*)d_in[6];
    const float* ob   = (const float*)d_in[7];
    const float* Wout = (const float*)d_in[8];
    const float* bout = (const float*)d_in[9];
    float* out = (float*)d_out;

    // Workspace: qkv bf16 18.9MB | (nsp-1) bf16 O-partials | nsp fp32 l |
    // transposed bf16 weights wqt (3.5MB) + wot (1.2MB).
    ushort* qkv = (ushort*)d_ws;
    const size_t qkvE = (size_t)3 * B_ * H_ * P_ * HD_;
    const size_t oE   = (size_t)B_ * H_ * P_ * HD_;
    const size_t lE   = (size_t)B_ * H_ * P_;
    const size_t wE   = (size_t)N1_ * D_ + (size_t)D_ * D_;
    ushort* obase = qkv + qkvE;
    const size_t need4 = (qkvE + 3 * oE + wE) * sizeof(ushort) + 4 * lE * sizeof(float);
    const int nsp = (ws_size >= need4) ? 4 : 2;
    ushort* op[4];
    float* lbase;
    if (nsp == 4) {
        op[0] = obase; op[1] = obase + oE; op[2] = obase + 2 * oE; op[3] = (ushort*)out;
        lbase = (float*)(obase + 3 * oE);
    } else {
        op[0] = obase; op[1] = (ushort*)out; op[2] = obase; op[3] = obase;
        lbase = (float*)(obase + oE);
    }
    float* lp[4] = {lbase, lbase + lE, lbase + 2 * lE, lbase + 3 * lE};
    ushort* wqt = (ushort*)(lp[0] + 4 * lE);       // [N1][D]
    ushort* wot = wqt + (size_t)N1_ * D_;          // [D][D]
    ushort* ln_buf = qkv;   // overlays dead q-region after attention

    precast_wt<<<dim3(N1_ / 64, D_ / 64), 256, 0, stream>>>(Wqkv, wqt, D_, N1_);
    precast_wt<<<dim3(D_ / 64, D_ / 64), 256, 0, stream>>>(Wout, wot, D_, D_);
    gemm_qkv_mfma<<<dim3(N1_ / 128, M_ / 128), 512, 0, stream>>>(x, wqt, qs, qb, ks, kb, qkv);
    attn_split<<<dim3(P_ / 256, B_ * H_, nsp), 512, 0, stream>>>(
        qkv, op[0], op[1], op[2], op[3], lp[0], lp[1], lp[2], lp[3]);
    ln_o<<<dim3(M_), 256, 0, stream>>>(
        op[0], op[1], op[2], op[3], lp[0], lp[1], lp[2], lp[3], nsp, ln_buf, osc, ob);
    gemm_out_mfma<<<dim3(D_ / 64, M_ / 64), 256, 0, stream>>>(ln_buf, wot, bout, out);
}